// Round 6
// baseline (260.354 us; speedup 1.0000x reference)
//
#include <hip/hip_runtime.h>
#include <hip/hip_fp16.h>
#include <math.h>

#define NN 10000
#define EE 160000
#define HID 128
constexpr int N128 = NN * HID;
constexpr int PSTR = 768;  // pack stride in halves: [k0 k1 k2 | h0 h1 h2]
constexpr int HOFF = 384;  // h region offset in pack (halves)

typedef _Float16 f16;
typedef f16 half8 __attribute__((ext_vector_type(8)));
typedef f16 f16x2 __attribute__((ext_vector_type(2)));
typedef float f32x4 __attribute__((ext_vector_type(4)));

#if __has_builtin(__builtin_amdgcn_fdot2)
__device__ inline float fdot2(f16x2 a, f16x2 b, float c) { return __builtin_amdgcn_fdot2(a, b, c, false); }
#else
__device__ inline float fdot2(f16x2 a, f16x2 b, float c) {
    return fmaf((float)a[0], (float)b[0], fmaf((float)a[1], (float)b[1], c));
}
#endif

// ---------------- degree count (by dst) ----------------
__global__ __launch_bounds__(256) void cnt_count(const int* __restrict__ dst, int* __restrict__ cnt) {
    int e = blockIdx.x * 256 + threadIdx.x;
    if (e < EE) atomicAdd(&cnt[dst[e]], 1);
}

__global__ __launch_bounds__(256) void make_dinv(const int* __restrict__ cnt, float* __restrict__ dinv) {
    int i = blockIdx.x * 256 + threadIdx.x;
    if (i < NN) dinv[i] = rsqrtf((float)cnt[i] + 1.0f);  // +1 self-loop
}

// ---------------- single-block exclusive scan -> rowptr ----------------
__global__ __launch_bounds__(256) void scan_rowptr(const int* __restrict__ cnt, int* __restrict__ rowptr) {
    __shared__ int part[256];
    const int PER = (NN + 255) / 256;  // 40
    int t = threadIdx.x;
    int base = t * PER;
    int sum = 0;
    for (int i = 0; i < PER; ++i) { int idx = base + i; if (idx < NN) sum += cnt[idx]; }
    part[t] = sum;
    __syncthreads();
    for (int ofs = 1; ofs < 256; ofs <<= 1) {
        int v = (t >= ofs) ? part[t - ofs] : 0;
        __syncthreads();
        part[t] += v;
        __syncthreads();
    }
    int run = (t > 0) ? part[t - 1] : 0;
    for (int i = 0; i < PER; ++i) {
        int idx = base + i;
        if (idx <= NN) rowptr[idx] = run;
        if (idx < NN) run += cnt[idx];
    }
}

__global__ __launch_bounds__(256) void scatter_edges(const int* __restrict__ ei,
                                                     const int* __restrict__ rowptr,
                                                     int* __restrict__ fill,
                                                     int* __restrict__ esorted) {
    int e = blockIdx.x * 256 + threadIdx.x;
    if (e < EE) {
        int s = ei[e], d = ei[EE + e];
        int pos = rowptr[d] + atomicAdd(&fill[d], 1);
        esorted[pos] = s;
    }
}

// ---------------- LPT schedule: counting sort nodes by degree descending ----------------
__global__ __launch_bounds__(256) void hist_deg(const int* __restrict__ cnt, int* __restrict__ hist) {
    int i = blockIdx.x * 256 + threadIdx.x;
    if (i < NN) atomicAdd(&hist[min(cnt[i], 63)], 1);
}

__global__ void scan_desc(const int* __restrict__ hist, int* __restrict__ binoff) {
    if (threadIdx.x == 0) {
        int run = 0;
        for (int b = 63; b >= 0; --b) { binoff[b] = run; run += hist[b]; }
    }
}

__global__ __launch_bounds__(256) void make_perm(const int* __restrict__ cnt, const int* __restrict__ binoff,
                                                 int* __restrict__ fill64, int* __restrict__ perm) {
    int i = blockIdx.x * 256 + threadIdx.x;
    if (i < NN) {
        int b = min(cnt[i], 63);
        perm[binoff[b] + atomicAdd(&fill64[b], 1)] = i;
    }
}

// ---------------- weight prep: Wt[mat][oc][k] = fp16(W[k][oc]), 10 matrices ----------------
__global__ __launch_bounds__(256) void wprep(const float* __restrict__ W1, const float* __restrict__ Wq,
                                             const float* __restrict__ Wk, const float* __restrict__ Wv,
                                             f16* __restrict__ Wt) {
    int b = blockIdx.x;  // 0=W1, 1..3=Wq[l], 4..6=Wk[l], 7..9=Wv[l]
    const float* src = (b == 0) ? W1
                     : (b < 4)  ? Wq + (size_t)(b - 1) * 16384
                     : (b < 7)  ? Wk + (size_t)(b - 4) * 16384
                                : Wv + (size_t)(b - 7) * 16384;
    f16* dst = Wt + (size_t)b * 16384;
    int t = threadIdx.x;
    int oc = t >> 1;
    int k0 = (t & 1) * 64;
    for (int kk = 0; kk < 64; ++kk) {
        int k = k0 + kk;
        dst[oc * 128 + k] = (f16)src[k * 128 + oc];
    }
}

// ---------------- x -> fp16 ----------------
__global__ __launch_bounds__(256) void tohalf(const float* __restrict__ in, __half* __restrict__ outh) {
    int i = blockIdx.x * 256 + threadIdx.x;
    if (i < N128 / 2) {
        float2 f = ((const float2*)in)[i];
        ((__half2*)outh)[i] = __floats2half2_rn(f.x, f.y);
    }
}

// ---------------- MFMA GEMM: out[n][oc] = sum_k in[n][k] * W[k][oc] + (rs*)bias[oc] ----------------
// in: fp16 [nrows][128] rows at stride ldi; Wt: fp16 [oc][k]; mode 0=f32, 1=f16+relu, 2=f16 raw
struct GJob { const f16* in; const f16* Wt; const float* bias; const float* rowscale; void* out; int ldi; int ldo; int mode; };
struct GJobs { GJob j[7]; };

__global__ __launch_bounds__(256) void gemm_mfma(GJobs jobs, int nrows) {
    const GJob jb = jobs.j[blockIdx.y];
    __shared__ f16 Xl[64 * 128];
    __shared__ f16 Wl[128 * 128];
    const int t = threadIdx.x;
    const int row0 = blockIdx.x * 64;

    half8 zero8;
#pragma unroll
    for (int z = 0; z < 8; ++z) zero8[z] = (f16)0.f;

#pragma unroll
    for (int it = 0; it < 4; ++it) {
        int idx = t + it * 256;
        int r = idx >> 4, c = idx & 15;
        int gr = row0 + r;
        half8 v = zero8;
        if (gr < nrows) v = *(const half8*)(jb.in + (size_t)gr * jb.ldi + c * 8);
        *(half8*)((char*)Xl + r * 256 + ((c * 16) ^ ((r & 7) << 4))) = v;
    }
#pragma unroll
    for (int it = 0; it < 8; ++it) {
        int idx = t + it * 256;
        int r = idx >> 4, c = idx & 15;
        half8 v = *(const half8*)(jb.Wt + (size_t)r * 128 + c * 8);
        *(half8*)((char*)Wl + r * 256 + ((c * 16) ^ ((r & 7) << 4))) = v;
    }
    __syncthreads();

    const int w = t >> 6, l = t & 63;
    const int lr = l & 15;
    const int lk = l >> 4;

    f32x4 acc[8];
#pragma unroll
    for (int tn = 0; tn < 8; ++tn)
#pragma unroll
        for (int i = 0; i < 4; ++i) acc[tn][i] = 0.f;

    const int arow = w * 16 + lr;
    const int axor = (arow & 7) << 4;
    const int bxor = (lr & 7) << 4;

#pragma unroll
    for (int ks = 0; ks < 4; ++ks) {
        int koff = (ks * 4 + lk) * 16;
        half8 a = *(const half8*)((const char*)Xl + arow * 256 + (koff ^ axor));
#pragma unroll
        for (int tn = 0; tn < 8; ++tn) {
            int oc = tn * 16 + lr;
            half8 b = *(const half8*)((const char*)Wl + oc * 256 + (koff ^ bxor));
            acc[tn] = __builtin_amdgcn_mfma_f32_16x16x32_f16(a, b, acc[tn], 0, 0, 0);
        }
    }

    const int rbase = row0 + w * 16 + (lk << 2);
    float brs[4];
#pragma unroll
    for (int i = 0; i < 4; ++i)
        brs[i] = jb.rowscale ? ((rbase + i < nrows) ? jb.rowscale[rbase + i] : 0.f) : 1.0f;
    float bsv[8];
#pragma unroll
    for (int tn = 0; tn < 8; ++tn) bsv[tn] = jb.bias[tn * 16 + lr];

    if (jb.mode == 0) {
        float* op = (float*)jb.out;
#pragma unroll
        for (int tn = 0; tn < 8; ++tn)
#pragma unroll
            for (int i = 0; i < 4; ++i) {
                int gr = rbase + i;
                if (gr < nrows) op[(size_t)gr * jb.ldo + tn * 16 + lr] = acc[tn][i] + brs[i] * bsv[tn];
            }
    } else if (jb.mode == 1) {
        f16* op = (f16*)jb.out;
#pragma unroll
        for (int tn = 0; tn < 8; ++tn)
#pragma unroll
            for (int i = 0; i < 4; ++i) {
                int gr = rbase + i;
                if (gr < nrows) op[(size_t)gr * jb.ldo + tn * 16 + lr] = (f16)fmaxf(acc[tn][i] + brs[i] * bsv[tn], 0.f);
            }
    } else {
        f16* op = (f16*)jb.out;
#pragma unroll
        for (int tn = 0; tn < 8; ++tn)
#pragma unroll
            for (int i = 0; i < 4; ++i) {
                int gr = rbase + i;
                if (gr < nrows) op[(size_t)gr * jb.ldo + tn * 16 + lr] = (f16)(acc[tn][i] + brs[i] * bsv[tn]);
            }
    }
}

// ---------------- layer-1 GCN aggregation + srow: S=dvd*sum dvs*h0[s]; srow=dvd*sum dvs ----------------
__global__ __launch_bounds__(256) void sgather(
    const int* __restrict__ rowptr, const int* __restrict__ esorted,
    const int* __restrict__ perm, const float* __restrict__ dinv,
    const f16* __restrict__ hsrc /* pack + HOFF */, f16* __restrict__ Sh, float* __restrict__ srow) {
    int wid = (blockIdx.x * 256 + threadIdx.x) >> 6;
    int lane = threadIdx.x & 63;
    if (wid >= NN) return;
    int d = perm[wid];
    int i0 = rowptr[d], i1 = rowptr[d + 1];
    int nE = i1 - i0 + 1;  // + self-loop (last)
    float dvd = dinv[d];
    float ax = 0.f, ay = 0.f, ssum = 0.f;
    auto srcof = [&](int j) -> int { return (j < nE - 1) ? esorted[i0 + j] : d; };
    auto hload = [&](int s) -> f16x2 { return *(const f16x2*)(hsrc + (size_t)s * PSTR + lane * 2); };

    int sA0 = srcof(0), sA1 = srcof(1);
    float dA0 = dinv[sA0], dA1 = dinv[sA1];
    f16x2 hA0 = hload(sA0);
    f16x2 hA1 = (nE > 1) ? hload(sA1) : hA0;

    for (int j0 = 0; j0 < nE; j0 += 2) {
        bool v2 = j0 + 2 < nE, v3 = j0 + 3 < nE;
        float dB0 = 0.f, dB1 = 0.f;
        f16x2 hB0 = hA0, hB1 = hA1;
        if (v2) { int s = srcof(j0 + 2); dB0 = dinv[s]; hB0 = hload(s); }
        if (v3) { int s = srcof(j0 + 3); dB1 = dinv[s]; hB1 = hload(s); }
        ax = fmaf(dA0, (float)hA0[0], ax); ay = fmaf(dA0, (float)hA0[1], ay); ssum += dA0;
        if (j0 + 1 < nE) { ax = fmaf(dA1, (float)hA1[0], ax); ay = fmaf(dA1, (float)hA1[1], ay); ssum += dA1; }
        dA0 = dB0; dA1 = dB1; hA0 = hB0; hA1 = hB1;
    }
    f16x2 o; o[0] = (f16)(dvd * ax); o[1] = (f16)(dvd * ay);
    *(f16x2*)(Sh + (size_t)d * 128 + lane * 2) = o;
    if (lane == 0) srow[d] = dvd * ssum;
}

// ---------------- node attention (deferred V), 2-pair pipeline: u[d] = sum_e norm * sum_l a_l h_l[s] ----------------
template<int L>
__global__ __launch_bounds__(256) void node_attn3(
    const int* __restrict__ rowptr, const int* __restrict__ esorted,
    const int* __restrict__ perm, const float* __restrict__ dinv,
    const f16* __restrict__ qh, const f16* __restrict__ pack,
    f16* __restrict__ uh) {
    int wid = (blockIdx.x * 256 + threadIdx.x) >> 6;
    int lane = threadIdx.x & 63;
    if (wid >= NN) return;
    int d = perm[wid];
    int i0 = rowptr[d], i1 = rowptr[d + 1];
    int nE = i1 - i0 + 1;  // + self-loop (last)
    float dvd = dinv[d];
    f16x2 q2 = *(const f16x2*)(qh + (size_t)d * 128 + lane * 2);
    float ax = 0.f, ay = 0.f;

    auto srcof = [&](int j) -> int { return (j < nE - 1) ? esorted[i0 + j] : d; };
    auto loadsrc = [&](int s, f16x2 (&k2)[L], f16x2 (&hh)[L]) {
        const f16* bp = pack + (size_t)s * PSTR + lane * 2;
#pragma unroll
        for (int l = 0; l < L; ++l) {
            k2[l] = *(const f16x2*)(bp + l * 128);
            hh[l] = *(const f16x2*)(bp + HOFF + l * 128);
        }
    };
    auto compute = [&](float dvs, const f16x2 (&k2)[L], const f16x2 (&hh)[L]) {
        float sc[L];
#pragma unroll
        for (int l = 0; l < L; ++l) {
            float p = fdot2(q2, k2[l], 0.f);
            p += __shfl_xor(p, 1);
            p += __shfl_xor(p, 2);
            p += __shfl_xor(p, 4);
            sc[l] = p * 0.25f;  // 1/sqrt(16)
        }
        float m = sc[0];
#pragma unroll
        for (int l = 1; l < L; ++l) m = fmaxf(m, sc[l]);
        float den = 0.f;
#pragma unroll
        for (int l = 0; l < L; ++l) { sc[l] = __expf(sc[l] - m); den += sc[l]; }
        float w = dvs * __builtin_amdgcn_rcpf(den);
#pragma unroll
        for (int l = 0; l < L; ++l) {
            float wl = sc[l] * w;
            ax = fmaf(wl, (float)hh[l][0], ax);
            ay = fmaf(wl, (float)hh[l][1], ay);
        }
    };

    f16x2 kA0[L], hA0[L], kA1[L], hA1[L];
    int sA0 = srcof(0), sA1 = srcof(1);
    float dA0 = dinv[sA0], dA1 = dinv[sA1];
    loadsrc(sA0, kA0, hA0);
    if (nE > 1) loadsrc(sA1, kA1, hA1);

    for (int j0 = 0; j0 < nE; j0 += 2) {
        f16x2 kB0[L], hB0[L], kB1[L], hB1[L];
        float dB0 = 0.f, dB1 = 0.f;
        bool v2 = j0 + 2 < nE, v3 = j0 + 3 < nE;
#pragma unroll
        for (int l = 0; l < L; ++l) { kB0[l] = kA0[l]; hB0[l] = hA0[l]; kB1[l] = kA1[l]; hB1[l] = hA1[l]; }
        if (v2) { int s = srcof(j0 + 2); dB0 = dinv[s]; loadsrc(s, kB0, hB0); }
        if (v3) { int s = srcof(j0 + 3); dB1 = dinv[s]; loadsrc(s, kB1, hB1); }
        compute(dA0, kA0, hA0);
        if (j0 + 1 < nE) compute(dA1, kA1, hA1);
        dA0 = dB0; dA1 = dB1;
#pragma unroll
        for (int l = 0; l < L; ++l) { kA0[l] = kB0[l]; hA0[l] = hB0[l]; kA1[l] = kB1[l]; hA1[l] = hB1[l]; }
    }
    f16x2 o; o[0] = (f16)(dvd * ax); o[1] = (f16)(dvd * ay);
    *(f16x2*)(uh + (size_t)d * 128 + lane * 2) = o;
}

// ---------------- final: logits + log_softmax (fp16 input, post-relu) ----------------
__global__ __launch_bounds__(256) void final_out(const __half* __restrict__ xin,
                                                 const float* __restrict__ W2,
                                                 const float* __restrict__ b2,
                                                 float* __restrict__ out) {
    int wid = (blockIdx.x * 256 + threadIdx.x) >> 6;
    int lane = threadIdx.x & 63;
    if (wid >= NN) return;
    const __half2* xr = (const __half2*)(xin + (size_t)wid * HID);
    float acc = b2[lane];
#pragma unroll 8
    for (int i = 0; i < 64; ++i) {
        float2 xv = __half22float2(xr[i]);
        acc = fmaf(xv.x, W2[(2 * i) * 64 + lane], acc);
        acc = fmaf(xv.y, W2[(2 * i + 1) * 64 + lane], acc);
    }
    float m = acc;
#pragma unroll
    for (int sft = 32; sft; sft >>= 1) m = fmaxf(m, __shfl_xor(m, sft));
    float e = __expf(acc - m), den = e;
#pragma unroll
    for (int sft = 32; sft; sft >>= 1) den += __shfl_xor(den, sft);
    out[(size_t)wid * 64 + lane] = acc - m - logf(den);
}

extern "C" void kernel_launch(void* const* d_in, const int* in_sizes, int n_in,
                              void* d_out, int out_size, void* d_ws, size_t ws_size,
                              hipStream_t stream) {
    (void)in_sizes; (void)n_in; (void)out_size; (void)ws_size;
    const float* x  = (const float*)d_in[0];
    const int*   ei = (const int*)d_in[1];
    const float* W1 = (const float*)d_in[2];
    const float* b1 = (const float*)d_in[3];
    const float* Wq = (const float*)d_in[4];
    const float* bq = (const float*)d_in[5];
    const float* Wk = (const float*)d_in[6];
    const float* bk = (const float*)d_in[7];
    const float* Wv = (const float*)d_in[8];
    const float* bv = (const float*)d_in[9];
    const float* W2 = (const float*)d_in[10];
    const float* b2 = (const float*)d_in[11];
    float* out = (float*)d_out;

    // workspace layout (4-byte words)
    int*    cnt     = (int*)d_ws;                  // 16384
    int*    fill    = cnt + 16384;                 // 16384
    int*    hist    = fill + 16384;                // 64
    int*    fill64  = hist + 64;                   // 64
    int*    binoff  = fill64 + 64;                 // 64
    int*    rowptr  = binoff + 64;                 // 16384
    int*    esorted = rowptr + 16384;              // 163840
    int*    perm    = esorted + 163840;            // 16384
    float*  dinv    = (float*)(perm + 16384);      // 16384
    float*  srow    = dinv + 16384;                // 16384
    f16*    xh      = (f16*)(srow + 16384);        // N128 halves
    f16*    pack    = xh + N128;                   // NN x 768 halves
    f16*    Sh      = pack + (size_t)NN * PSTR;    // N128
    f16*    qh      = Sh + N128;                   // N128
    f16*    uh      = qh + N128;                   // N128
    f16*    lvh3    = uh + N128;                   // N128
    f16*    Wt      = lvh3 + N128;                 // 10 x 16384

    // zero cnt, fill, hist, fill64 (contiguous)
    hipMemsetAsync(cnt, 0, (2 * 16384 + 128) * sizeof(int), stream);

    cnt_count<<<(EE + 255) / 256, 256, 0, stream>>>(ei + EE, cnt);
    make_dinv<<<(NN + 255) / 256, 256, 0, stream>>>(cnt, dinv);
    scan_rowptr<<<1, 256, 0, stream>>>(cnt, rowptr);
    scatter_edges<<<(EE + 255) / 256, 256, 0, stream>>>(ei, rowptr, fill, esorted);
    hist_deg<<<(NN + 255) / 256, 256, 0, stream>>>(cnt, hist);
    scan_desc<<<1, 64, 0, stream>>>(hist, binoff);
    make_perm<<<(NN + 255) / 256, 256, 0, stream>>>(cnt, binoff, fill64, perm);

    wprep<<<10, 256, 0, stream>>>(W1, Wq, Wk, Wv, Wt);
    tohalf<<<(N128 / 2 + 255) / 256, 256, 0, stream>>>(x, (__half*)xh);

    const int gx = (NN + 63) / 64;  // 157
    auto WT = [&](int m) { return Wt + (size_t)m * 16384; };  // 0=W1,1..3=Wq,4..6=Wk,7..9=Wv
    auto H  = [&](int lev) { return pack + HOFF + lev * 128; };  // h-level base (stride PSTR)
    auto K  = [&](int lev) { return pack + lev * 128; };         // k-level base (stride PSTR)

    {   // h0 = relu(x @ W1 + b1) -> pack
        GJobs jobs{};
        jobs.j[0] = {xh, WT(0), b1, nullptr, H(0), HID, PSTR, 1};
        gemm_mfma<<<dim3(gx, 1), 256, 0, stream>>>(jobs, NN);
    }

    const int nblocks = (NN * 64 + 255) / 256;

    // ---- layer 1 (L=1: softmax over 1 level == identity -> GCN, deferred Wv1) ----
    sgather<<<nblocks, 256, 0, stream>>>(rowptr, esorted, perm, dinv, pack + HOFF, Sh, srow);
    {   // h1 = relu(S @ Wv1 + srow*bv1) -> pack
        GJobs jobs{};
        jobs.j[0] = {Sh, WT(7), bv, srow, H(1), HID, PSTR, 1};
        gemm_mfma<<<dim3(gx, 1), 256, 0, stream>>>(jobs, NN);
    }

    // ---- layers 2,3: q/k GEMMs -> attention (aggregate raw h) -> deferred Wv GEMM ----
    for (int l = 1; l < 3; ++l) {
        int L = l + 1;
        GJobs jobs{};
        jobs.j[0] = {H(L - 1), WT(1 + l), bq + l * HID, nullptr, qh, PSTR, HID, 2};
        for (int lev = 0; lev < L; ++lev)
            jobs.j[1 + lev] = {H(lev), WT(4 + l), bk + l * HID, nullptr, K(lev), PSTR, PSTR, 2};
        gemm_mfma<<<dim3(gx, 1 + L), 256, 0, stream>>>(jobs, NN);

        if (L == 2) node_attn3<2><<<nblocks, 256, 0, stream>>>(rowptr, esorted, perm, dinv, qh, pack, uh);
        if (L == 3) node_attn3<3><<<nblocks, 256, 0, stream>>>(rowptr, esorted, perm, dinv, qh, pack, uh);

        GJobs vjob{};
        if (L == 2) vjob.j[0] = {uh, WT(7 + l), bv + l * HID, srow, H(2), HID, PSTR, 1};
        else        vjob.j[0] = {uh, WT(7 + l), bv + l * HID, srow, lvh3, HID, HID, 1};
        gemm_mfma<<<dim3(gx, 1), 256, 0, stream>>>(vjob, NN);
    }

    final_out<<<(NN * 64 + 255) / 256, 256, 0, stream>>>((const __half*)lvh3, W2, b2, out);
}

// Round 7
// 217.536 us; speedup vs baseline: 1.1968x; 1.1968x over previous
//
#include <hip/hip_runtime.h>
#include <hip/hip_fp16.h>
#include <math.h>

#define NN 10000
#define EE 160000
#define HID 128
constexpr int N128 = NN * HID;
constexpr int PSTR = 768;  // pack stride in halves: [k0 k1 k2 | h0 h1 h2]
constexpr int HOFF = 384;  // h region offset in pack (halves)

typedef _Float16 f16;
typedef f16 half8 __attribute__((ext_vector_type(8)));
typedef f16 f16x2 __attribute__((ext_vector_type(2)));
typedef float f32x4 __attribute__((ext_vector_type(4)));

#if __has_builtin(__builtin_amdgcn_fdot2)
__device__ inline float fdot2(f16x2 a, f16x2 b, float c) { return __builtin_amdgcn_fdot2(a, b, c, false); }
#else
__device__ inline float fdot2(f16x2 a, f16x2 b, float c) {
    return fmaf((float)a[0], (float)b[0], fmaf((float)a[1], (float)b[1], c));
}
#endif

// ---------------- zero cnt+fill (custom: rocclr fillBuffer is ~44us in-graph) ----------------
__global__ __launch_bounds__(256) void zero_ws(int4* __restrict__ p) {
    p[blockIdx.x * 256 + threadIdx.x] = make_int4(0, 0, 0, 0);  // 32 blocks x 256 x 16B = 128KB
}

// ---------------- degree count (by dst) ----------------
__global__ __launch_bounds__(256) void cnt_count(const int* __restrict__ dst, int* __restrict__ cnt) {
    int e = blockIdx.x * 256 + threadIdx.x;
    if (e < EE) atomicAdd(&cnt[dst[e]], 1);
}

// ---------------- single-block exclusive scan -> rowptr, + dinv fused ----------------
__global__ __launch_bounds__(256) void scan_rowptr(const int* __restrict__ cnt, int* __restrict__ rowptr,
                                                   float* __restrict__ dinv) {
    __shared__ int part[256];
    const int PER = (NN + 255) / 256;  // 40
    int t = threadIdx.x;
    int base = t * PER;
    int sum = 0;
    for (int i = 0; i < PER; ++i) {
        int idx = base + i;
        if (idx < NN) {
            int c = cnt[idx];
            sum += c;
            dinv[idx] = rsqrtf((float)c + 1.0f);  // +1 self-loop
        }
    }
    part[t] = sum;
    __syncthreads();
    for (int ofs = 1; ofs < 256; ofs <<= 1) {
        int v = (t >= ofs) ? part[t - ofs] : 0;
        __syncthreads();
        part[t] += v;
        __syncthreads();
    }
    int run = (t > 0) ? part[t - 1] : 0;
    for (int i = 0; i < PER; ++i) {
        int idx = base + i;
        if (idx <= NN) rowptr[idx] = run;
        if (idx < NN) run += cnt[idx];
    }
}

__global__ __launch_bounds__(256) void scatter_edges(const int* __restrict__ ei,
                                                     const int* __restrict__ rowptr,
                                                     int* __restrict__ fill,
                                                     int* __restrict__ esorted) {
    int e = blockIdx.x * 256 + threadIdx.x;
    if (e < EE) {
        int s = ei[e], d = ei[EE + e];
        int pos = rowptr[d] + atomicAdd(&fill[d], 1);
        esorted[pos] = s;
    }
}

// ---------------- weight prep: Wt[mat][oc][k] = fp16(W[k][oc]), 10 matrices ----------------
__global__ __launch_bounds__(256) void wprep(const float* __restrict__ W1, const float* __restrict__ Wq,
                                             const float* __restrict__ Wk, const float* __restrict__ Wv,
                                             f16* __restrict__ Wt) {
    int b = blockIdx.x;  // 0=W1, 1..3=Wq[l], 4..6=Wk[l], 7..9=Wv[l]
    const float* src = (b == 0) ? W1
                     : (b < 4)  ? Wq + (size_t)(b - 1) * 16384
                     : (b < 7)  ? Wk + (size_t)(b - 4) * 16384
                                : Wv + (size_t)(b - 7) * 16384;
    f16* dst = Wt + (size_t)b * 16384;
    int t = threadIdx.x;
    int oc = t >> 1;
    int k0 = (t & 1) * 64;
    for (int kk = 0; kk < 64; ++kk) {
        int k = k0 + kk;
        dst[oc * 128 + k] = (f16)src[k * 128 + oc];
    }
}

// ---------------- MFMA GEMM: out[n][oc] = sum_k in[n][k] * W[k][oc] + (rs*)bias[oc] ----------------
// in: [nrows][128] rows at stride ldi (f16, or f32 if inF32); Wt: f16 [oc][k]; mode 0=f32, 1=f16+relu, 2=f16 raw
struct GJob { const void* in; const f16* Wt; const float* bias; const float* rowscale; void* out; int ldi; int ldo; int mode; int inF32; };
struct GJobs { GJob j[7]; };

__global__ __launch_bounds__(256) void gemm_mfma(GJobs jobs, int nrows) {
    const GJob jb = jobs.j[blockIdx.y];
    __shared__ f16 Xl[64 * 128];
    __shared__ f16 Wl[128 * 128];
    const int t = threadIdx.x;
    const int row0 = blockIdx.x * 64;

    half8 zero8;
#pragma unroll
    for (int z = 0; z < 8; ++z) zero8[z] = (f16)0.f;

#pragma unroll
    for (int it = 0; it < 4; ++it) {
        int idx = t + it * 256;
        int r = idx >> 4, c = idx & 15;
        int gr = row0 + r;
        half8 v = zero8;
        if (gr < nrows) {
            if (jb.inF32) {
                const float* fin = (const float*)jb.in + (size_t)gr * jb.ldi + c * 8;
                float4 f0 = ((const float4*)fin)[0];
                float4 f1 = ((const float4*)fin)[1];
                v[0] = (f16)f0.x; v[1] = (f16)f0.y; v[2] = (f16)f0.z; v[3] = (f16)f0.w;
                v[4] = (f16)f1.x; v[5] = (f16)f1.y; v[6] = (f16)f1.z; v[7] = (f16)f1.w;
            } else {
                v = *(const half8*)((const f16*)jb.in + (size_t)gr * jb.ldi + c * 8);
            }
        }
        *(half8*)((char*)Xl + r * 256 + ((c * 16) ^ ((r & 7) << 4))) = v;
    }
#pragma unroll
    for (int it = 0; it < 8; ++it) {
        int idx = t + it * 256;
        int r = idx >> 4, c = idx & 15;
        half8 v = *(const half8*)(jb.Wt + (size_t)r * 128 + c * 8);
        *(half8*)((char*)Wl + r * 256 + ((c * 16) ^ ((r & 7) << 4))) = v;
    }
    __syncthreads();

    const int w = t >> 6, l = t & 63;
    const int lr = l & 15;
    const int lk = l >> 4;

    f32x4 acc[8];
#pragma unroll
    for (int tn = 0; tn < 8; ++tn)
#pragma unroll
        for (int i = 0; i < 4; ++i) acc[tn][i] = 0.f;

    const int arow = w * 16 + lr;
    const int axor = (arow & 7) << 4;
    const int bxor = (lr & 7) << 4;

#pragma unroll
    for (int ks = 0; ks < 4; ++ks) {
        int koff = (ks * 4 + lk) * 16;
        half8 a = *(const half8*)((const char*)Xl + arow * 256 + (koff ^ axor));
#pragma unroll
        for (int tn = 0; tn < 8; ++tn) {
            int oc = tn * 16 + lr;
            half8 b = *(const half8*)((const char*)Wl + oc * 256 + (koff ^ bxor));
            acc[tn] = __builtin_amdgcn_mfma_f32_16x16x32_f16(a, b, acc[tn], 0, 0, 0);
        }
    }

    const int rbase = row0 + w * 16 + (lk << 2);
    float brs[4];
#pragma unroll
    for (int i = 0; i < 4; ++i)
        brs[i] = jb.rowscale ? ((rbase + i < nrows) ? jb.rowscale[rbase + i] : 0.f) : 1.0f;
    float bsv[8];
#pragma unroll
    for (int tn = 0; tn < 8; ++tn) bsv[tn] = jb.bias[tn * 16 + lr];

    if (jb.mode == 0) {
        float* op = (float*)jb.out;
#pragma unroll
        for (int tn = 0; tn < 8; ++tn)
#pragma unroll
            for (int i = 0; i < 4; ++i) {
                int gr = rbase + i;
                if (gr < nrows) op[(size_t)gr * jb.ldo + tn * 16 + lr] = acc[tn][i] + brs[i] * bsv[tn];
            }
    } else if (jb.mode == 1) {
        f16* op = (f16*)jb.out;
#pragma unroll
        for (int tn = 0; tn < 8; ++tn)
#pragma unroll
            for (int i = 0; i < 4; ++i) {
                int gr = rbase + i;
                if (gr < nrows) op[(size_t)gr * jb.ldo + tn * 16 + lr] = (f16)fmaxf(acc[tn][i] + brs[i] * bsv[tn], 0.f);
            }
    } else {
        f16* op = (f16*)jb.out;
#pragma unroll
        for (int tn = 0; tn < 8; ++tn)
#pragma unroll
            for (int i = 0; i < 4; ++i) {
                int gr = rbase + i;
                if (gr < nrows) op[(size_t)gr * jb.ldo + tn * 16 + lr] = (f16)(acc[tn][i] + brs[i] * bsv[tn]);
            }
    }
}

// ---------------- layer-1 GCN aggregation + srow: S=dvd*sum dvs*h0[s]; srow=dvd*sum dvs ----------------
__global__ __launch_bounds__(256) void sgather(
    const int* __restrict__ rowptr, const int* __restrict__ esorted,
    const float* __restrict__ dinv,
    const f16* __restrict__ hsrc /* pack + HOFF */, f16* __restrict__ Sh, float* __restrict__ srow) {
    int d = (blockIdx.x * 256 + threadIdx.x) >> 6;
    int lane = threadIdx.x & 63;
    if (d >= NN) return;
    int i0 = rowptr[d], i1 = rowptr[d + 1];
    int nE = i1 - i0 + 1;  // + self-loop (last)
    float dvd = dinv[d];
    float ax = 0.f, ay = 0.f, ssum = 0.f;
    auto srcof = [&](int j) -> int { return (j < nE - 1) ? esorted[i0 + j] : d; };
    auto hload = [&](int s) -> f16x2 { return *(const f16x2*)(hsrc + (size_t)s * PSTR + lane * 2); };

    int sA0 = srcof(0), sA1 = srcof(1);
    float dA0 = dinv[sA0], dA1 = dinv[sA1];
    f16x2 hA0 = hload(sA0);
    f16x2 hA1 = (nE > 1) ? hload(sA1) : hA0;

    for (int j0 = 0; j0 < nE; j0 += 2) {
        bool v2 = j0 + 2 < nE, v3 = j0 + 3 < nE;
        float dB0 = 0.f, dB1 = 0.f;
        f16x2 hB0 = hA0, hB1 = hA1;
        if (v2) { int s = srcof(j0 + 2); dB0 = dinv[s]; hB0 = hload(s); }
        if (v3) { int s = srcof(j0 + 3); dB1 = dinv[s]; hB1 = hload(s); }
        ax = fmaf(dA0, (float)hA0[0], ax); ay = fmaf(dA0, (float)hA0[1], ay); ssum += dA0;
        if (j0 + 1 < nE) { ax = fmaf(dA1, (float)hA1[0], ax); ay = fmaf(dA1, (float)hA1[1], ay); ssum += dA1; }
        dA0 = dB0; dA1 = dB1; hA0 = hB0; hA1 = hB1;
    }
    f16x2 o; o[0] = (f16)(dvd * ax); o[1] = (f16)(dvd * ay);
    *(f16x2*)(Sh + (size_t)d * 128 + lane * 2) = o;
    if (lane == 0) srow[d] = dvd * ssum;
}

// ---------------- node attention (deferred V), 2-pair pipeline ----------------
template<int L>
__global__ __launch_bounds__(256) void node_attn3(
    const int* __restrict__ rowptr, const int* __restrict__ esorted,
    const float* __restrict__ dinv,
    const f16* __restrict__ qh, const f16* __restrict__ pack,
    f16* __restrict__ uh) {
    int d = (blockIdx.x * 256 + threadIdx.x) >> 6;
    int lane = threadIdx.x & 63;
    if (d >= NN) return;
    int i0 = rowptr[d], i1 = rowptr[d + 1];
    int nE = i1 - i0 + 1;  // + self-loop (last)
    float dvd = dinv[d];
    f16x2 q2 = *(const f16x2*)(qh + (size_t)d * 128 + lane * 2);
    float ax = 0.f, ay = 0.f;

    auto srcof = [&](int j) -> int { return (j < nE - 1) ? esorted[i0 + j] : d; };
    auto loadsrc = [&](int s, f16x2 (&k2)[L], f16x2 (&hh)[L]) {
        const f16* bp = pack + (size_t)s * PSTR + lane * 2;
#pragma unroll
        for (int l = 0; l < L; ++l) {
            k2[l] = *(const f16x2*)(bp + l * 128);
            hh[l] = *(const f16x2*)(bp + HOFF + l * 128);
        }
    };
    auto compute = [&](float dvs, const f16x2 (&k2)[L], const f16x2 (&hh)[L]) {
        float sc[L];
#pragma unroll
        for (int l = 0; l < L; ++l) {
            float p = fdot2(q2, k2[l], 0.f);
            p += __shfl_xor(p, 1);
            p += __shfl_xor(p, 2);
            p += __shfl_xor(p, 4);
            sc[l] = p * 0.25f;  // 1/sqrt(16)
        }
        float m = sc[0];
#pragma unroll
        for (int l = 1; l < L; ++l) m = fmaxf(m, sc[l]);
        float den = 0.f;
#pragma unroll
        for (int l = 0; l < L; ++l) { sc[l] = __expf(sc[l] - m); den += sc[l]; }
        float w = dvs * __builtin_amdgcn_rcpf(den);
#pragma unroll
        for (int l = 0; l < L; ++l) {
            float wl = sc[l] * w;
            ax = fmaf(wl, (float)hh[l][0], ax);
            ay = fmaf(wl, (float)hh[l][1], ay);
        }
    };

    f16x2 kA0[L], hA0[L], kA1[L], hA1[L];
    int sA0 = srcof(0), sA1 = srcof(1);
    float dA0 = dinv[sA0], dA1 = dinv[sA1];
    loadsrc(sA0, kA0, hA0);
    if (nE > 1) loadsrc(sA1, kA1, hA1);

    for (int j0 = 0; j0 < nE; j0 += 2) {
        f16x2 kB0[L], hB0[L], kB1[L], hB1[L];
        float dB0 = 0.f, dB1 = 0.f;
        bool v2 = j0 + 2 < nE, v3 = j0 + 3 < nE;
#pragma unroll
        for (int l = 0; l < L; ++l) { kB0[l] = kA0[l]; hB0[l] = hA0[l]; kB1[l] = kA1[l]; hB1[l] = hA1[l]; }
        if (v2) { int s = srcof(j0 + 2); dB0 = dinv[s]; loadsrc(s, kB0, hB0); }
        if (v3) { int s = srcof(j0 + 3); dB1 = dinv[s]; loadsrc(s, kB1, hB1); }
        compute(dA0, kA0, hA0);
        if (j0 + 1 < nE) compute(dA1, kA1, hA1);
        dA0 = dB0; dA1 = dB1;
#pragma unroll
        for (int l = 0; l < L; ++l) { kA0[l] = kB0[l]; hA0[l] = hB0[l]; kA1[l] = kB1[l]; hA1[l] = hB1[l]; }
    }
    f16x2 o; o[0] = (f16)(dvd * ax); o[1] = (f16)(dvd * ay);
    *(f16x2*)(uh + (size_t)d * 128 + lane * 2) = o;
}

// ---------------- final: logits + log_softmax (fp16 input, post-relu) ----------------
__global__ __launch_bounds__(256) void final_out(const __half* __restrict__ xin,
                                                 const float* __restrict__ W2,
                                                 const float* __restrict__ b2,
                                                 float* __restrict__ out) {
    int wid = (blockIdx.x * 256 + threadIdx.x) >> 6;
    int lane = threadIdx.x & 63;
    if (wid >= NN) return;
    const __half2* xr = (const __half2*)(xin + (size_t)wid * HID);
    float acc = b2[lane];
#pragma unroll 8
    for (int i = 0; i < 64; ++i) {
        float2 xv = __half22float2(xr[i]);
        acc = fmaf(xv.x, W2[(2 * i) * 64 + lane], acc);
        acc = fmaf(xv.y, W2[(2 * i + 1) * 64 + lane], acc);
    }
    float m = acc;
#pragma unroll
    for (int sft = 32; sft; sft >>= 1) m = fmaxf(m, __shfl_xor(m, sft));
    float e = __expf(acc - m), den = e;
#pragma unroll
    for (int sft = 32; sft; sft >>= 1) den += __shfl_xor(den, sft);
    out[(size_t)wid * 64 + lane] = acc - m - logf(den);
}

extern "C" void kernel_launch(void* const* d_in, const int* in_sizes, int n_in,
                              void* d_out, int out_size, void* d_ws, size_t ws_size,
                              hipStream_t stream) {
    (void)in_sizes; (void)n_in; (void)out_size; (void)ws_size;
    const float* x  = (const float*)d_in[0];
    const int*   ei = (const int*)d_in[1];
    const float* W1 = (const float*)d_in[2];
    const float* b1 = (const float*)d_in[3];
    const float* Wq = (const float*)d_in[4];
    const float* bq = (const float*)d_in[5];
    const float* Wk = (const float*)d_in[6];
    const float* bk = (const float*)d_in[7];
    const float* Wv = (const float*)d_in[8];
    const float* bv = (const float*)d_in[9];
    const float* W2 = (const float*)d_in[10];
    const float* b2 = (const float*)d_in[11];
    float* out = (float*)d_out;

    // workspace layout (4-byte words)
    int*    cnt     = (int*)d_ws;                  // 16384
    int*    fill    = cnt + 16384;                 // 16384  (cnt+fill zeroed together)
    int*    rowptr  = fill + 16384;                // 16384 (NN+1)
    int*    esorted = rowptr + 16384;              // 163840
    float*  dinv    = (float*)(esorted + 163840);  // 16384
    float*  srow    = dinv + 16384;                // 16384
    f16*    pack    = (f16*)(srow + 16384);        // NN x 768 halves
    f16*    Sh      = pack + (size_t)NN * PSTR;    // N128
    f16*    qh      = Sh + N128;                   // N128
    f16*    uh      = qh + N128;                   // N128
    f16*    lvh3    = uh + N128;                   // N128
    f16*    Wt      = lvh3 + N128;                 // 10 x 16384

    zero_ws<<<32, 256, 0, stream>>>((int4*)cnt);  // cnt + fill = 32768 ints = 8192 int4
    cnt_count<<<(EE + 255) / 256, 256, 0, stream>>>(ei + EE, cnt);
    scan_rowptr<<<1, 256, 0, stream>>>(cnt, rowptr, dinv);
    scatter_edges<<<(EE + 255) / 256, 256, 0, stream>>>(ei, rowptr, fill, esorted);
    wprep<<<10, 256, 0, stream>>>(W1, Wq, Wk, Wv, Wt);

    const int gx = (NN + 63) / 64;  // 157
    auto WT = [&](int m) { return Wt + (size_t)m * 16384; };  // 0=W1,1..3=Wq,4..6=Wk,7..9=Wv
    auto H  = [&](int lev) { return pack + HOFF + lev * 128; };  // h-level base (stride PSTR)
    auto K  = [&](int lev) { return pack + lev * 128; };         // k-level base (stride PSTR)

    {   // h0 = relu(x @ W1 + b1) -> pack   (reads f32 x directly)
        GJobs jobs{};
        jobs.j[0] = {x, WT(0), b1, nullptr, H(0), HID, PSTR, 1, 1};
        gemm_mfma<<<dim3(gx, 1), 256, 0, stream>>>(jobs, NN);
    }

    const int nblocks = (NN * 64 + 255) / 256;

    // ---- layer 1 (L=1: softmax over 1 level == identity -> GCN, deferred Wv1) ----
    sgather<<<nblocks, 256, 0, stream>>>(rowptr, esorted, dinv, pack + HOFF, Sh, srow);
    {   // h1 = relu(S @ Wv1 + srow*bv1) -> pack
        GJobs jobs{};
        jobs.j[0] = {Sh, WT(7), bv, srow, H(1), HID, PSTR, 1, 0};
        gemm_mfma<<<dim3(gx, 1), 256, 0, stream>>>(jobs, NN);
    }

    // ---- layers 2,3: q/k GEMMs -> attention (aggregate raw h) -> deferred Wv GEMM ----
    for (int l = 1; l < 3; ++l) {
        int L = l + 1;
        GJobs jobs{};
        jobs.j[0] = {H(L - 1), WT(1 + l), bq + l * HID, nullptr, qh, PSTR, HID, 2, 0};
        for (int lev = 0; lev < L; ++lev)
            jobs.j[1 + lev] = {H(lev), WT(4 + l), bk + l * HID, nullptr, K(lev), PSTR, PSTR, 2, 0};
        gemm_mfma<<<dim3(gx, 1 + L), 256, 0, stream>>>(jobs, NN);

        if (L == 2) node_attn3<2><<<nblocks, 256, 0, stream>>>(rowptr, esorted, dinv, qh, pack, uh);
        if (L == 3) node_attn3<3><<<nblocks, 256, 0, stream>>>(rowptr, esorted, dinv, qh, pack, uh);

        GJobs vjob{};
        if (L == 2) vjob.j[0] = {uh, WT(7 + l), bv + l * HID, srow, H(2), HID, PSTR, 1, 0};
        else        vjob.j[0] = {uh, WT(7 + l), bv + l * HID, srow, lvh3, HID, HID, 1, 0};
        gemm_mfma<<<dim3(gx, 1), 256, 0, stream>>>(vjob, NN);
    }

    final_out<<<(NN * 64 + 255) / 256, 256, 0, stream>>>((const __half*)lvh3, W2, b2, out);
}

// Round 8
// 206.097 us; speedup vs baseline: 1.2633x; 1.0555x over previous
//
#include <hip/hip_runtime.h>
#include <hip/hip_fp16.h>
#include <math.h>

#define NN 10000
#define EE 160000
#define HID 128
constexpr int N128 = NN * HID;
constexpr int PSTR = 768;  // pack stride in halves: [k0 k1 k2 | h0 h1 h2]
constexpr int HOFF = 384;  // h region offset in pack (halves)

typedef _Float16 f16;
typedef f16 half8 __attribute__((ext_vector_type(8)));
typedef f16 f16x2 __attribute__((ext_vector_type(2)));
typedef float f32x4 __attribute__((ext_vector_type(4)));

#if __has_builtin(__builtin_amdgcn_fdot2)
__device__ inline float fdot2(f16x2 a, f16x2 b, float c) { return __builtin_amdgcn_fdot2(a, b, c, false); }
#else
__device__ inline float fdot2(f16x2 a, f16x2 b, float c) {
    return fmaf((float)a[0], (float)b[0], fmaf((float)a[1], (float)b[1], c));
}
#endif

// ---------------- zero cnt+fill (custom: rocclr fillBuffer is ~44us in-graph) ----------------
__global__ __launch_bounds__(256) void zero_ws(int4* __restrict__ p) {
    p[blockIdx.x * 256 + threadIdx.x] = make_int4(0, 0, 0, 0);
}

// ---------------- degree count (by dst) ----------------
__global__ __launch_bounds__(256) void cnt_count(const int* __restrict__ dst, int* __restrict__ cnt) {
    int e = blockIdx.x * 256 + threadIdx.x;
    if (e < EE) atomicAdd(&cnt[dst[e]], 1);
}

// ---------------- single-block exclusive scan -> rowptr, + dinv fused ----------------
__global__ __launch_bounds__(256) void scan_rowptr(const int* __restrict__ cnt, int* __restrict__ rowptr,
                                                   float* __restrict__ dinv) {
    __shared__ int part[256];
    const int PER = (NN + 255) / 256;  // 40
    int t = threadIdx.x;
    int base = t * PER;
    int sum = 0;
    for (int i = 0; i < PER; ++i) {
        int idx = base + i;
        if (idx < NN) {
            int c = cnt[idx];
            sum += c;
            dinv[idx] = rsqrtf((float)c + 1.0f);  // +1 self-loop
        }
    }
    part[t] = sum;
    __syncthreads();
    for (int ofs = 1; ofs < 256; ofs <<= 1) {
        int v = (t >= ofs) ? part[t - ofs] : 0;
        __syncthreads();
        part[t] += v;
        __syncthreads();
    }
    int run = (t > 0) ? part[t - 1] : 0;
    for (int i = 0; i < PER; ++i) {
        int idx = base + i;
        if (idx <= NN) rowptr[idx] = run;
        if (idx < NN) run += cnt[idx];
    }
}

__global__ __launch_bounds__(256) void scatter_edges(const int* __restrict__ ei,
                                                     const int* __restrict__ rowptr,
                                                     int* __restrict__ fill,
                                                     int* __restrict__ esorted) {
    int e = blockIdx.x * 256 + threadIdx.x;
    if (e < EE) {
        int s = ei[e], d = ei[EE + e];
        int pos = rowptr[d] + atomicAdd(&fill[d], 1);
        esorted[pos] = s;
    }
}

// ---------------- weight prep: Wt[mat][oc][k] = fp16(W[k][oc]); mat 10 = W2 (64 cols) ----------------
__global__ __launch_bounds__(256) void wprep(const float* __restrict__ W1, const float* __restrict__ Wq,
                                             const float* __restrict__ Wk, const float* __restrict__ Wv,
                                             const float* __restrict__ W2, f16* __restrict__ Wt) {
    int b = blockIdx.x;  // 0=W1, 1..3=Wq[l], 4..6=Wk[l], 7..9=Wv[l], 10=W2
    f16* dst = Wt + (size_t)b * 16384;
    int t = threadIdx.x;
    if (b == 10) {
        int oc = t & 63, k0 = (t >> 6) * 32;
        for (int kk = 0; kk < 32; ++kk) {
            int k = k0 + kk;
            dst[oc * 128 + k] = (f16)W2[(size_t)k * 64 + oc];
        }
        return;
    }
    const float* src = (b == 0) ? W1
                     : (b < 4)  ? Wq + (size_t)(b - 1) * 16384
                     : (b < 7)  ? Wk + (size_t)(b - 4) * 16384
                                : Wv + (size_t)(b - 7) * 16384;
    int oc = t >> 1;
    int k0 = (t & 1) * 64;
    for (int kk = 0; kk < 64; ++kk) {
        int k = k0 + kk;
        dst[oc * 128 + k] = (f16)src[k * 128 + oc];
    }
}

// ---------------- MFMA GEMM ----------------
// mode 0=f32 out, 1=f16+relu, 2=f16 raw, 3=fused final: relu -> @W2t -> +b2 -> log_softmax -> f32 out
struct GJob {
    const void* in; const f16* Wt; const float* bias; const float* rowscale;
    void* out; int ldi; int ldo; int mode; int inF32;
    const f16* Wt2; const float* bias2;
};
struct GJobs { GJob j[7]; };

__global__ __launch_bounds__(256) void gemm_mfma(GJobs jobs, int nrows) {
    const GJob jb = jobs.j[blockIdx.y];
    __shared__ f16 Xl[64 * 128];
    __shared__ f16 Wl[128 * 128];
    const int t = threadIdx.x;
    const int row0 = blockIdx.x * 64;

    half8 zero8;
#pragma unroll
    for (int z = 0; z < 8; ++z) zero8[z] = (f16)0.f;

#pragma unroll
    for (int it = 0; it < 4; ++it) {
        int idx = t + it * 256;
        int r = idx >> 4, c = idx & 15;
        int gr = row0 + r;
        half8 v = zero8;
        if (gr < nrows) {
            if (jb.inF32) {
                const float* fin = (const float*)jb.in + (size_t)gr * jb.ldi + c * 8;
                float4 f0 = ((const float4*)fin)[0];
                float4 f1 = ((const float4*)fin)[1];
                v[0] = (f16)f0.x; v[1] = (f16)f0.y; v[2] = (f16)f0.z; v[3] = (f16)f0.w;
                v[4] = (f16)f1.x; v[5] = (f16)f1.y; v[6] = (f16)f1.z; v[7] = (f16)f1.w;
            } else {
                v = *(const half8*)((const f16*)jb.in + (size_t)gr * jb.ldi + c * 8);
            }
        }
        *(half8*)((char*)Xl + r * 256 + ((c * 16) ^ ((r & 7) << 4))) = v;
    }
#pragma unroll
    for (int it = 0; it < 8; ++it) {
        int idx = t + it * 256;
        int r = idx >> 4, c = idx & 15;
        half8 v = *(const half8*)(jb.Wt + (size_t)r * 128 + c * 8);
        *(half8*)((char*)Wl + r * 256 + ((c * 16) ^ ((r & 7) << 4))) = v;
    }
    __syncthreads();

    const int w = t >> 6, l = t & 63;
    const int lr = l & 15;
    const int lk = l >> 4;

    f32x4 acc[8];
#pragma unroll
    for (int tn = 0; tn < 8; ++tn)
#pragma unroll
        for (int i = 0; i < 4; ++i) acc[tn][i] = 0.f;

    const int arow = w * 16 + lr;
    const int axor = (arow & 7) << 4;
    const int bxor = (lr & 7) << 4;

#pragma unroll
    for (int ks = 0; ks < 4; ++ks) {
        int koff = (ks * 4 + lk) * 16;
        half8 a = *(const half8*)((const char*)Xl + arow * 256 + (koff ^ axor));
#pragma unroll
        for (int tn = 0; tn < 8; ++tn) {
            int oc = tn * 16 + lr;
            half8 b = *(const half8*)((const char*)Wl + oc * 256 + (koff ^ bxor));
            acc[tn] = __builtin_amdgcn_mfma_f32_16x16x32_f16(a, b, acc[tn], 0, 0, 0);
        }
    }

    const int rbase = row0 + w * 16 + (lk << 2);
    float brs[4];
#pragma unroll
    for (int i = 0; i < 4; ++i)
        brs[i] = jb.rowscale ? ((rbase + i < nrows) ? jb.rowscale[rbase + i] : 0.f) : 1.0f;
    float bsv[8];
#pragma unroll
    for (int tn = 0; tn < 8; ++tn) bsv[tn] = jb.bias[tn * 16 + lr];

    if (jb.mode == 0) {
        float* op = (float*)jb.out;
#pragma unroll
        for (int tn = 0; tn < 8; ++tn)
#pragma unroll
            for (int i = 0; i < 4; ++i) {
                int gr = rbase + i;
                if (gr < nrows) op[(size_t)gr * jb.ldo + tn * 16 + lr] = acc[tn][i] + brs[i] * bsv[tn];
            }
    } else if (jb.mode == 1) {
        f16* op = (f16*)jb.out;
#pragma unroll
        for (int tn = 0; tn < 8; ++tn)
#pragma unroll
            for (int i = 0; i < 4; ++i) {
                int gr = rbase + i;
                if (gr < nrows) op[(size_t)gr * jb.ldo + tn * 16 + lr] = (f16)fmaxf(acc[tn][i] + brs[i] * bsv[tn], 0.f);
            }
    } else if (jb.mode == 2) {
        f16* op = (f16*)jb.out;
#pragma unroll
        for (int tn = 0; tn < 8; ++tn)
#pragma unroll
            for (int i = 0; i < 4; ++i) {
                int gr = rbase + i;
                if (gr < nrows) op[(size_t)gr * jb.ldo + tn * 16 + lr] = (f16)(acc[tn][i] + brs[i] * bsv[tn]);
            }
    } else {
        // mode 3: h3 = relu(acc + brs*bsv) -> Xl (swizzled); stage W2t -> Wl; MFMA vs W2t; +b2; log_softmax
        __syncthreads();  // everyone done reading Xl/Wl
#pragma unroll
        for (int tn = 0; tn < 8; ++tn)
#pragma unroll
            for (int i = 0; i < 4; ++i) {
                f16 v = (f16)fmaxf(acc[tn][i] + brs[i] * bsv[tn], 0.f);
                int lrow = w * 16 + (lk << 2) + i;
                int col = tn * 16 + lr;
                int byte = lrow * 256 + ((((col >> 3) * 16) ^ ((lrow & 7) << 4))) + (col & 7) * 2;
                *(f16*)((char*)Xl + byte) = v;
            }
#pragma unroll
        for (int it = 0; it < 4; ++it) {  // W2t: 64 rows x 16 chunks
            int idx = t + it * 256;
            int r = idx >> 4, c = idx & 15;
            half8 v = *(const half8*)(jb.Wt2 + (size_t)r * 128 + c * 8);
            *(half8*)((char*)Wl + r * 256 + ((c * 16) ^ ((r & 7) << 4))) = v;
        }
        __syncthreads();

        f32x4 acc2[4];
#pragma unroll
        for (int tn = 0; tn < 4; ++tn)
#pragma unroll
            for (int i = 0; i < 4; ++i) acc2[tn][i] = 0.f;
#pragma unroll
        for (int ks = 0; ks < 4; ++ks) {
            int koff = (ks * 4 + lk) * 16;
            half8 a = *(const half8*)((const char*)Xl + arow * 256 + (koff ^ axor));
#pragma unroll
            for (int tn = 0; tn < 4; ++tn) {
                int oc = tn * 16 + lr;
                half8 b = *(const half8*)((const char*)Wl + oc * 256 + (koff ^ bxor));
                acc2[tn] = __builtin_amdgcn_mfma_f32_16x16x32_f16(a, b, acc2[tn], 0, 0, 0);
            }
        }
        float bs2[4];
#pragma unroll
        for (int tn = 0; tn < 4; ++tn) bs2[tn] = jb.bias2[tn * 16 + lr];
#pragma unroll
        for (int i = 0; i < 4; ++i) {
            float lg[4];
#pragma unroll
            for (int tn = 0; tn < 4; ++tn) lg[tn] = acc2[tn][i] + bs2[tn];
            float m = fmaxf(fmaxf(lg[0], lg[1]), fmaxf(lg[2], lg[3]));
#pragma unroll
            for (int sft = 1; sft <= 8; sft <<= 1) m = fmaxf(m, __shfl_xor(m, sft));
            float den = 0.f;
#pragma unroll
            for (int tn = 0; tn < 4; ++tn) den += __expf(lg[tn] - m);
#pragma unroll
            for (int sft = 1; sft <= 8; sft <<= 1) den += __shfl_xor(den, sft);
            float lden = logf(den);
            int gr = rbase + i;
            if (gr < nrows) {
                float* op = (float*)jb.out + (size_t)gr * jb.ldo;
#pragma unroll
                for (int tn = 0; tn < 4; ++tn) op[tn * 16 + lr] = lg[tn] - m - lden;
            }
        }
    }
}

// ---------------- layer-1 GCN aggregation, 4-edge batched pipeline ----------------
__global__ __launch_bounds__(256) void sgather4(
    const int* __restrict__ rowptr, const int* __restrict__ esorted,
    const float* __restrict__ dinv,
    const f16* __restrict__ hsrc /* pack + HOFF */, f16* __restrict__ Sh, float* __restrict__ srow) {
    int d = (blockIdx.x * 256 + threadIdx.x) >> 6;
    int lane = threadIdx.x & 63;
    if (d >= NN) return;
    int i0 = rowptr[d], i1 = rowptr[d + 1];
    int nE = i1 - i0 + 1;  // + self-loop (j == nE-1); j >= nE padded with weight 0
    float dvd = dinv[d];
    float ax = 0.f, ay = 0.f, ssum = 0.f;

    auto ld_idx = [&](int jb, int (&s)[4], float (&dv)[4]) {
#pragma unroll
        for (int u = 0; u < 4; ++u) {
            int j = jb + u;
            int ss = (j < nE - 1) ? esorted[i0 + j] : d;
            s[u] = ss;
            dv[u] = (j < nE) ? dinv[ss] : 0.f;
        }
    };
    auto ld_dat = [&](const int (&s)[4], f16x2 (&hh)[4]) {
#pragma unroll
        for (int u = 0; u < 4; ++u)
            hh[u] = *(const f16x2*)(hsrc + (size_t)s[u] * PSTR + lane * 2);
    };
    auto comp = [&](const float (&dv)[4], const f16x2 (&hh)[4]) {
#pragma unroll
        for (int u = 0; u < 4; ++u) {
            ax = fmaf(dv[u], (float)hh[u][0], ax);
            ay = fmaf(dv[u], (float)hh[u][1], ay);
            ssum += dv[u];
        }
    };

    int sA[4], sB[4], sC[4], sD[4];
    float wA[4], wB[4], wC[4], wD[4];
    f16x2 hA[4], hB[4];
    ld_idx(0, sA, wA); ld_dat(sA, hA);
    ld_idx(4, sB, wB);
    for (int base = 0; base < nE; base += 8) {
        ld_idx(base + 8, sC, wC);
        ld_dat(sB, hB);
        comp(wA, hA);
        ld_idx(base + 12, sD, wD);
        ld_dat(sC, hA);
        comp(wB, hB);
#pragma unroll
        for (int u = 0; u < 4; ++u) { wA[u] = wC[u]; sB[u] = sD[u]; wB[u] = wD[u]; }
    }
    f16x2 o; o[0] = (f16)(dvd * ax); o[1] = (f16)(dvd * ay);
    *(f16x2*)(Sh + (size_t)d * 128 + lane * 2) = o;
    if (lane == 0) srow[d] = dvd * ssum;
}

// ---------------- node attention (deferred V), 4-edge batched, branchless-padded pipeline ----------------
template<int L>
__global__ __launch_bounds__(256) void node_attn4(
    const int* __restrict__ rowptr, const int* __restrict__ esorted,
    const float* __restrict__ dinv,
    const f16* __restrict__ qh, const f16* __restrict__ pack,
    f16* __restrict__ uh) {
    int d = (blockIdx.x * 256 + threadIdx.x) >> 6;
    int lane = threadIdx.x & 63;
    if (d >= NN) return;
    int i0 = rowptr[d], i1 = rowptr[d + 1];
    int nE = i1 - i0 + 1;  // self-loop at j == nE-1; j >= nE padded (weight 0, loads node d)
    float dvd = dinv[d];
    f16x2 q2 = *(const f16x2*)(qh + (size_t)d * 128 + lane * 2);
    float ax = 0.f, ay = 0.f;

    auto ld_idx = [&](int jb, int (&s)[4], float (&dv)[4]) {
#pragma unroll
        for (int u = 0; u < 4; ++u) {
            int j = jb + u;
            int ss = (j < nE - 1) ? esorted[i0 + j] : d;
            s[u] = ss;
            dv[u] = (j < nE) ? dinv[ss] : 0.f;
        }
    };
    auto ld_dat = [&](const int (&s)[4], f16x2 (&k2)[4][L], f16x2 (&hh)[4][L]) {
#pragma unroll
        for (int u = 0; u < 4; ++u) {
            const f16* bp = pack + (size_t)s[u] * PSTR + lane * 2;
#pragma unroll
            for (int l = 0; l < L; ++l) {
                k2[u][l] = *(const f16x2*)(bp + l * 128);
                hh[u][l] = *(const f16x2*)(bp + HOFF + l * 128);
            }
        }
    };
    auto comp = [&](const float (&dv)[4], const f16x2 (&k2)[4][L], const f16x2 (&hh)[4][L]) {
#pragma unroll
        for (int u = 0; u < 4; ++u) {
            float sc[L];
#pragma unroll
            for (int l = 0; l < L; ++l) {
                float p = fdot2(q2, k2[u][l], 0.f);
                p += __shfl_xor(p, 1);
                p += __shfl_xor(p, 2);
                p += __shfl_xor(p, 4);
                sc[l] = p * 0.25f;  // 1/sqrt(16)
            }
            float m = sc[0];
#pragma unroll
            for (int l = 1; l < L; ++l) m = fmaxf(m, sc[l]);
            float den = 0.f;
#pragma unroll
            for (int l = 0; l < L; ++l) { sc[l] = __expf(sc[l] - m); den += sc[l]; }
            float wgt = dv[u] * __builtin_amdgcn_rcpf(den);
#pragma unroll
            for (int l = 0; l < L; ++l) {
                float wl = sc[l] * wgt;
                ax = fmaf(wl, (float)hh[u][l][0], ax);
                ay = fmaf(wl, (float)hh[u][l][1], ay);
            }
        }
    };

    int sA[4], sB[4], sC[4], sD[4];
    float wA[4], wB[4], wC[4], wD[4];
    f16x2 kA[4][L], hA[4][L], kB[4][L], hB[4][L];
    ld_idx(0, sA, wA); ld_dat(sA, kA, hA);
    ld_idx(4, sB, wB);
    for (int base = 0; base < nE; base += 8) {
        ld_idx(base + 8, sC, wC);
        ld_dat(sB, kB, hB);
        comp(wA, kA, hA);
        ld_idx(base + 12, sD, wD);
        ld_dat(sC, kA, hA);
        comp(wB, kB, hB);
#pragma unroll
        for (int u = 0; u < 4; ++u) { wA[u] = wC[u]; sB[u] = sD[u]; wB[u] = wD[u]; }
    }
    f16x2 o; o[0] = (f16)(dvd * ax); o[1] = (f16)(dvd * ay);
    *(f16x2*)(uh + (size_t)d * 128 + lane * 2) = o;
}

extern "C" void kernel_launch(void* const* d_in, const int* in_sizes, int n_in,
                              void* d_out, int out_size, void* d_ws, size_t ws_size,
                              hipStream_t stream) {
    (void)in_sizes; (void)n_in; (void)out_size; (void)ws_size;
    const float* x  = (const float*)d_in[0];
    const int*   ei = (const int*)d_in[1];
    const float* W1 = (const float*)d_in[2];
    const float* b1 = (const float*)d_in[3];
    const float* Wq = (const float*)d_in[4];
    const float* bq = (const float*)d_in[5];
    const float* Wk = (const float*)d_in[6];
    const float* bk = (const float*)d_in[7];
    const float* Wv = (const float*)d_in[8];
    const float* bv = (const float*)d_in[9];
    const float* W2 = (const float*)d_in[10];
    const float* b2 = (const float*)d_in[11];
    float* out = (float*)d_out;

    // workspace layout (4-byte words)
    int*    cnt     = (int*)d_ws;                  // 16384
    int*    fill    = cnt + 16384;                 // 16384 (cnt+fill zeroed together)
    int*    rowptr  = fill + 16384;                // 16384 (NN+1)
    int*    esorted = rowptr + 16384;              // 163840 (EE + pad; padded reads guarded by value)
    float*  dinv    = (float*)(esorted + 163840);  // 16384
    float*  srow    = dinv + 16384;                // 16384
    f16*    pack    = (f16*)(srow + 16384);        // NN x 768 halves
    f16*    Sh      = pack + (size_t)NN * PSTR;    // N128
    f16*    qh      = Sh + N128;                   // N128
    f16*    uh      = qh + N128;                   // N128
    f16*    Wt      = uh + N128;                   // 11 x 16384

    zero_ws<<<32, 256, 0, stream>>>((int4*)cnt);  // cnt + fill = 32768 ints
    cnt_count<<<(EE + 255) / 256, 256, 0, stream>>>(ei + EE, cnt);
    scan_rowptr<<<1, 256, 0, stream>>>(cnt, rowptr, dinv);
    scatter_edges<<<(EE + 255) / 256, 256, 0, stream>>>(ei, rowptr, fill, esorted);
    wprep<<<11, 256, 0, stream>>>(W1, Wq, Wk, Wv, W2, Wt);

    const int gx = (NN + 63) / 64;  // 157
    auto WT = [&](int m) { return Wt + (size_t)m * 16384; };  // 0=W1,1..3=Wq,4..6=Wk,7..9=Wv,10=W2
    auto H  = [&](int lev) { return pack + HOFF + lev * 128; };  // h-level base (stride PSTR)
    auto K  = [&](int lev) { return pack + lev * 128; };         // k-level base (stride PSTR)

    {   // h0 = relu(x @ W1 + b1) -> pack  (reads f32 x directly)
        GJobs jobs{};
        jobs.j[0] = {x, WT(0), b1, nullptr, H(0), HID, PSTR, 1, 1, nullptr, nullptr};
        gemm_mfma<<<dim3(gx, 1), 256, 0, stream>>>(jobs, NN);
    }

    const int nblocks = (NN * 64 + 255) / 256;

    // ---- layer 1 (L=1: softmax over 1 level == identity -> GCN, deferred Wv1) ----
    sgather4<<<nblocks, 256, 0, stream>>>(rowptr, esorted, dinv, pack + HOFF, Sh, srow);
    {   // h1 = relu(S @ Wv1 + srow*bv1) -> pack
        GJobs jobs{};
        jobs.j[0] = {Sh, WT(7), bv, srow, H(1), HID, PSTR, 1, 0, nullptr, nullptr};
        gemm_mfma<<<dim3(gx, 1), 256, 0, stream>>>(jobs, NN);
    }

    // ---- layers 2,3: q/k GEMMs -> attention (aggregate raw h) -> deferred Wv GEMM ----
    for (int l = 1; l < 3; ++l) {
        int L = l + 1;
        GJobs jobs{};
        jobs.j[0] = {H(L - 1), WT(1 + l), bq + l * HID, nullptr, qh, PSTR, HID, 2, 0, nullptr, nullptr};
        for (int lev = 0; lev < L; ++lev)
            jobs.j[1 + lev] = {H(lev), WT(4 + l), bk + l * HID, nullptr, K(lev), PSTR, PSTR, 2, 0, nullptr, nullptr};
        gemm_mfma<<<dim3(gx, 1 + L), 256, 0, stream>>>(jobs, NN);

        if (L == 2) node_attn4<2><<<nblocks, 256, 0, stream>>>(rowptr, esorted, dinv, qh, pack, uh);
        if (L == 3) node_attn4<3><<<nblocks, 256, 0, stream>>>(rowptr, esorted, dinv, qh, pack, uh);

        GJobs vjob{};
        if (L == 2) {
            // h2 = relu(u @ Wv2 + srow*bv2) -> pack
            vjob.j[0] = {uh, WT(7 + l), bv + l * HID, srow, H(2), HID, PSTR, 1, 0, nullptr, nullptr};
        } else {
            // fused: h3 = relu(u @ Wv3 + srow*bv3); out = log_softmax(h3 @ W2 + b2)
            vjob.j[0] = {uh, WT(7 + l), bv + l * HID, srow, out, HID, 64, 3, 0, WT(10), b2};
        }
        gemm_mfma<<<dim3(gx, 1), 256, 0, stream>>>(vjob, NN);
    }
}

// Round 9
// 168.988 us; speedup vs baseline: 1.5407x; 1.2196x over previous
//
#include <hip/hip_runtime.h>
#include <hip/hip_fp16.h>
#include <math.h>

#define NN 10000
#define EE 160000
#define HID 128
constexpr int N128 = NN * HID;
constexpr int PSTR = 768;  // pack stride in halves: [k0 k1 k2 | h0 h1 h2]
constexpr int HOFF = 384;  // h region offset in pack (halves)

typedef _Float16 f16;
typedef f16 half8 __attribute__((ext_vector_type(8)));
typedef f16 f16x2 __attribute__((ext_vector_type(2)));
typedef float f32x4 __attribute__((ext_vector_type(4)));

#if __has_builtin(__builtin_amdgcn_fdot2)
__device__ inline float fdot2(f16x2 a, f16x2 b, float c) { return __builtin_amdgcn_fdot2(a, b, c, false); }
#else
__device__ inline float fdot2(f16x2 a, f16x2 b, float c) {
    return fmaf((float)a[0], (float)b[0], fmaf((float)a[1], (float)b[1], c));
}
#endif

// ---------------- degree count (by dst) ----------------
__global__ __launch_bounds__(256) void cnt_count(const int* __restrict__ dst, int* __restrict__ cnt) {
    int e = blockIdx.x * 256 + threadIdx.x;
    if (e < EE) atomicAdd(&cnt[dst[e]], 1);
}

// ---------------- single-block exclusive scan -> rowptr, + dinv fused ----------------
__global__ __launch_bounds__(256) void scan_rowptr(const int* __restrict__ cnt, int* __restrict__ rowptr,
                                                   float* __restrict__ dinv) {
    __shared__ int part[256];
    const int PER = (NN + 255) / 256;  // 40
    int t = threadIdx.x;
    int base = t * PER;
    int sum = 0;
    for (int i = 0; i < PER; ++i) {
        int idx = base + i;
        if (idx < NN) {
            int c = cnt[idx];
            sum += c;
            dinv[idx] = rsqrtf((float)c + 1.0f);  // +1 self-loop
        }
    }
    part[t] = sum;
    __syncthreads();
    for (int ofs = 1; ofs < 256; ofs <<= 1) {
        int v = (t >= ofs) ? part[t - ofs] : 0;
        __syncthreads();
        part[t] += v;
        __syncthreads();
    }
    int run = (t > 0) ? part[t - 1] : 0;
    for (int i = 0; i < PER; ++i) {
        int idx = base + i;
        if (idx <= NN) rowptr[idx] = run;
        if (idx < NN) run += cnt[idx];
    }
}

__global__ __launch_bounds__(256) void scatter_edges(const int* __restrict__ ei,
                                                     const int* __restrict__ rowptr,
                                                     int* __restrict__ fill,
                                                     int* __restrict__ esorted) {
    int e = blockIdx.x * 256 + threadIdx.x;
    if (e < EE) {
        int s = ei[e], d = ei[EE + e];
        int pos = rowptr[d] + atomicAdd(&fill[d], 1);
        esorted[pos] = s;
    }
}

// ---------------- fused: weight prep (blocks 0..10) + zero cnt/fill (blocks 11..42) ----------------
__global__ __launch_bounds__(256) void prep_fused(const float* __restrict__ W1, const float* __restrict__ Wq,
                                                  const float* __restrict__ Wk, const float* __restrict__ Wv,
                                                  const float* __restrict__ W2, f16* __restrict__ Wt,
                                                  int4* __restrict__ zbuf) {
    int b = blockIdx.x;  // 0=W1, 1..3=Wq[l], 4..6=Wk[l], 7..9=Wv[l], 10=W2, 11..42 = zero 128KB
    int t = threadIdx.x;
    if (b >= 11) {
        zbuf[(b - 11) * 256 + t] = make_int4(0, 0, 0, 0);
        return;
    }
    f16* dst = Wt + (size_t)b * 16384;
    if (b == 10) {
        int oc = t & 63, k0 = (t >> 6) * 32;
        for (int kk = 0; kk < 32; ++kk) {
            int k = k0 + kk;
            dst[oc * 128 + k] = (f16)W2[(size_t)k * 64 + oc];
        }
        return;
    }
    const float* src = (b == 0) ? W1
                     : (b < 4)  ? Wq + (size_t)(b - 1) * 16384
                     : (b < 7)  ? Wk + (size_t)(b - 4) * 16384
                                : Wv + (size_t)(b - 7) * 16384;
    int oc = t >> 1;
    int k0 = (t & 1) * 64;
    for (int kk = 0; kk < 64; ++kk) {
        int k = k0 + kk;
        dst[oc * 128 + k] = (f16)src[k * 128 + oc];
    }
}

// ---------------- MFMA GEMM ----------------
// mode 0=f32 out, 1=f16+relu, 2=f16 raw, 3=fused final: relu -> @W2t -> +b2 -> log_softmax -> f32 out
struct GJob {
    const void* in; const f16* Wt; const float* bias; const float* rowscale;
    void* out; int ldi; int ldo; int mode; int inF32;
    const f16* Wt2; const float* bias2;
};
struct GJobs { GJob j[7]; };

__global__ __launch_bounds__(256) void gemm_mfma(GJobs jobs, int nrows) {
    const GJob jb = jobs.j[blockIdx.y];
    __shared__ f16 Xl[64 * 128];
    __shared__ f16 Wl[128 * 128];
    const int t = threadIdx.x;
    const int row0 = blockIdx.x * 64;

    half8 zero8;
#pragma unroll
    for (int z = 0; z < 8; ++z) zero8[z] = (f16)0.f;

#pragma unroll
    for (int it = 0; it < 4; ++it) {
        int idx = t + it * 256;
        int r = idx >> 4, c = idx & 15;
        int gr = row0 + r;
        half8 v = zero8;
        if (gr < nrows) {
            if (jb.inF32) {
                const float* fin = (const float*)jb.in + (size_t)gr * jb.ldi + c * 8;
                float4 f0 = ((const float4*)fin)[0];
                float4 f1 = ((const float4*)fin)[1];
                v[0] = (f16)f0.x; v[1] = (f16)f0.y; v[2] = (f16)f0.z; v[3] = (f16)f0.w;
                v[4] = (f16)f1.x; v[5] = (f16)f1.y; v[6] = (f16)f1.z; v[7] = (f16)f1.w;
            } else {
                v = *(const half8*)((const f16*)jb.in + (size_t)gr * jb.ldi + c * 8);
            }
        }
        *(half8*)((char*)Xl + r * 256 + ((c * 16) ^ ((r & 7) << 4))) = v;
    }
#pragma unroll
    for (int it = 0; it < 8; ++it) {
        int idx = t + it * 256;
        int r = idx >> 4, c = idx & 15;
        half8 v = *(const half8*)(jb.Wt + (size_t)r * 128 + c * 8);
        *(half8*)((char*)Wl + r * 256 + ((c * 16) ^ ((r & 7) << 4))) = v;
    }
    __syncthreads();

    const int w = t >> 6, l = t & 63;
    const int lr = l & 15;
    const int lk = l >> 4;

    f32x4 acc[8];
#pragma unroll
    for (int tn = 0; tn < 8; ++tn)
#pragma unroll
        for (int i = 0; i < 4; ++i) acc[tn][i] = 0.f;

    const int arow = w * 16 + lr;
    const int axor = (arow & 7) << 4;
    const int bxor = (lr & 7) << 4;

#pragma unroll
    for (int ks = 0; ks < 4; ++ks) {
        int koff = (ks * 4 + lk) * 16;
        half8 a = *(const half8*)((const char*)Xl + arow * 256 + (koff ^ axor));
#pragma unroll
        for (int tn = 0; tn < 8; ++tn) {
            int oc = tn * 16 + lr;
            half8 b = *(const half8*)((const char*)Wl + oc * 256 + (koff ^ bxor));
            acc[tn] = __builtin_amdgcn_mfma_f32_16x16x32_f16(a, b, acc[tn], 0, 0, 0);
        }
    }

    const int rbase = row0 + w * 16 + (lk << 2);
    float brs[4];
#pragma unroll
    for (int i = 0; i < 4; ++i)
        brs[i] = jb.rowscale ? ((rbase + i < nrows) ? jb.rowscale[rbase + i] : 0.f) : 1.0f;
    float bsv[8];
#pragma unroll
    for (int tn = 0; tn < 8; ++tn) bsv[tn] = jb.bias[tn * 16 + lr];

    if (jb.mode == 0) {
        float* op = (float*)jb.out;
#pragma unroll
        for (int tn = 0; tn < 8; ++tn)
#pragma unroll
            for (int i = 0; i < 4; ++i) {
                int gr = rbase + i;
                if (gr < nrows) op[(size_t)gr * jb.ldo + tn * 16 + lr] = acc[tn][i] + brs[i] * bsv[tn];
            }
    } else if (jb.mode == 1) {
        f16* op = (f16*)jb.out;
#pragma unroll
        for (int tn = 0; tn < 8; ++tn)
#pragma unroll
            for (int i = 0; i < 4; ++i) {
                int gr = rbase + i;
                if (gr < nrows) op[(size_t)gr * jb.ldo + tn * 16 + lr] = (f16)fmaxf(acc[tn][i] + brs[i] * bsv[tn], 0.f);
            }
    } else if (jb.mode == 2) {
        f16* op = (f16*)jb.out;
#pragma unroll
        for (int tn = 0; tn < 8; ++tn)
#pragma unroll
            for (int i = 0; i < 4; ++i) {
                int gr = rbase + i;
                if (gr < nrows) op[(size_t)gr * jb.ldo + tn * 16 + lr] = (f16)(acc[tn][i] + brs[i] * bsv[tn]);
            }
    } else {
        // mode 3: h3 = relu(acc + brs*bsv) -> Xl (swizzled); stage W2t -> Wl; MFMA vs W2t; +b2; log_softmax
        __syncthreads();  // everyone done reading Xl/Wl
#pragma unroll
        for (int tn = 0; tn < 8; ++tn)
#pragma unroll
            for (int i = 0; i < 4; ++i) {
                f16 v = (f16)fmaxf(acc[tn][i] + brs[i] * bsv[tn], 0.f);
                int lrow = w * 16 + (lk << 2) + i;
                int col = tn * 16 + lr;
                int byte = lrow * 256 + ((((col >> 3) * 16) ^ ((lrow & 7) << 4))) + (col & 7) * 2;
                *(f16*)((char*)Xl + byte) = v;
            }
#pragma unroll
        for (int it = 0; it < 4; ++it) {  // W2t: 64 rows x 16 chunks
            int idx = t + it * 256;
            int r = idx >> 4, c = idx & 15;
            half8 v = *(const half8*)(jb.Wt2 + (size_t)r * 128 + c * 8);
            *(half8*)((char*)Wl + r * 256 + ((c * 16) ^ ((r & 7) << 4))) = v;
        }
        __syncthreads();

        f32x4 acc2[4];
#pragma unroll
        for (int tn = 0; tn < 4; ++tn)
#pragma unroll
            for (int i = 0; i < 4; ++i) acc2[tn][i] = 0.f;
#pragma unroll
        for (int ks = 0; ks < 4; ++ks) {
            int koff = (ks * 4 + lk) * 16;
            half8 a = *(const half8*)((const char*)Xl + arow * 256 + (koff ^ axor));
#pragma unroll
            for (int tn = 0; tn < 4; ++tn) {
                int oc = tn * 16 + lr;
                half8 b = *(const half8*)((const char*)Wl + oc * 256 + (koff ^ bxor));
                acc2[tn] = __builtin_amdgcn_mfma_f32_16x16x32_f16(a, b, acc2[tn], 0, 0, 0);
            }
        }
        float bs2[4];
#pragma unroll
        for (int tn = 0; tn < 4; ++tn) bs2[tn] = jb.bias2[tn * 16 + lr];
#pragma unroll
        for (int i = 0; i < 4; ++i) {
            float lg[4];
#pragma unroll
            for (int tn = 0; tn < 4; ++tn) lg[tn] = acc2[tn][i] + bs2[tn];
            float m = fmaxf(fmaxf(lg[0], lg[1]), fmaxf(lg[2], lg[3]));
#pragma unroll
            for (int sft = 1; sft <= 8; sft <<= 1) m = fmaxf(m, __shfl_xor(m, sft));
            float den = 0.f;
#pragma unroll
            for (int tn = 0; tn < 4; ++tn) den += __expf(lg[tn] - m);
#pragma unroll
            for (int sft = 1; sft <= 8; sft <<= 1) den += __shfl_xor(den, sft);
            float lden = logf(den);
            int gr = rbase + i;
            if (gr < nrows) {
                float* op = (float*)jb.out + (size_t)gr * jb.ldo;
#pragma unroll
                for (int tn = 0; tn < 4; ++tn) op[tn * 16 + lr] = lg[tn] - m - lden;
            }
        }
    }
}

// ---------------- layer-1 GCN aggregation, quarter-wave (4 edges/wave) ----------------
__global__ __launch_bounds__(256) void sgather5(
    const int* __restrict__ rowptr, const int* __restrict__ esorted,
    const float* __restrict__ dinv,
    const f16* __restrict__ hsrc /* pack + HOFF */, f16* __restrict__ Sh, float* __restrict__ srow) {
    int d = (blockIdx.x * 256 + threadIdx.x) >> 6;
    int lam = threadIdx.x & 63;
    int qe = lam >> 4, le = lam & 15;
    if (d >= NN) return;
    int i0 = rowptr[d], nE = rowptr[d + 1] - i0 + 1;  // + self-loop (j == nE-1); j >= nE: w=0
    float dvd = dinv[d];
    float u[8];
#pragma unroll
    for (int i = 0; i < 8; ++i) u[i] = 0.f;
    float ssum = 0.f;

    auto ldb = [&](int b, float& w, half8& h) {
        int j = b + qe;
        int s = (j < nE - 1) ? esorted[i0 + j] : d;
        w = (j < nE) ? dinv[s] : 0.f;
        h = *(const half8*)(hsrc + (size_t)s * PSTR + le * 8);
    };
    auto cmp = [&](float w, const half8& h) {
#pragma unroll
        for (int i = 0; i < 8; ++i) u[i] = fmaf(w, (float)h[i], u[i]);
        ssum += w;
    };

    float wA, wB; half8 hA, hB;
    ldb(0, wA, hA);
    for (int b = 0; b < nE; b += 8) {
        ldb(b + 4, wB, hB);
        cmp(wA, hA);
        ldb(b + 8, wA, hA);
        cmp(wB, hB);
    }
    // reduce across the 4 edge-slots
#pragma unroll
    for (int i = 0; i < 8; ++i) {
        u[i] += __shfl_xor(u[i], 16);
        u[i] += __shfl_xor(u[i], 32);
    }
    ssum += __shfl_xor(ssum, 16);
    ssum += __shfl_xor(ssum, 32);
    if (qe == 0) {
        half8 o;
#pragma unroll
        for (int i = 0; i < 8; ++i) o[i] = (f16)(dvd * u[i]);
        *(half8*)(Sh + (size_t)d * 128 + le * 8) = o;
        if (le == 0) srow[d] = dvd * ssum;
    }
}

// ---------------- node attention (deferred V), quarter-wave: 4 edges/wave, 16B/lane ----------------
// lane: qe = lam>>4 (edge slot), le = lam&15 (channels [8*le,8*le+8), head = le>>1)
template<int L>
__global__ __launch_bounds__(256) void node_attn5(
    const int* __restrict__ rowptr, const int* __restrict__ esorted,
    const float* __restrict__ dinv,
    const f16* __restrict__ qh, const f16* __restrict__ pack,
    f16* __restrict__ uh) {
    int d = (blockIdx.x * 256 + threadIdx.x) >> 6;
    int lam = threadIdx.x & 63;
    int qe = lam >> 4, le = lam & 15;
    if (d >= NN) return;
    int i0 = rowptr[d], nE = rowptr[d + 1] - i0 + 1;  // self-loop at j == nE-1; j >= nE: w=0
    float dvd = dinv[d];
    half8 q8 = *(const half8*)(qh + (size_t)d * 128 + le * 8);
    const f16x2* qp = (const f16x2*)&q8;
    float u[8];
#pragma unroll
    for (int i = 0; i < 8; ++i) u[i] = 0.f;

    auto ldb = [&](int b, float& w, half8 (&k)[L], half8 (&h)[L]) {
        int j = b + qe;
        int s = (j < nE - 1) ? esorted[i0 + j] : d;
        w = (j < nE) ? dinv[s] : 0.f;
        const f16* bp = pack + (size_t)s * PSTR + le * 8;
#pragma unroll
        for (int l = 0; l < L; ++l) {
            k[l] = *(const half8*)(bp + l * 128);
            h[l] = *(const half8*)(bp + HOFF + l * 128);
        }
    };
    auto cmp = [&](float w, const half8 (&k)[L], const half8 (&h)[L]) {
        float sc[L];
#pragma unroll
        for (int l = 0; l < L; ++l) {
            const f16x2* kp = (const f16x2*)&k[l];
            float p = 0.f;
#pragma unroll
            for (int i = 0; i < 4; ++i) p = fdot2(qp[i], kp[i], p);
            p += __shfl_xor(p, 1);  // partner lane holds the head's other 8 channels
            sc[l] = p * 0.25f;      // 1/sqrt(16)
        }
        float m = sc[0];
#pragma unroll
        for (int l = 1; l < L; ++l) m = fmaxf(m, sc[l]);
        float den = 0.f;
#pragma unroll
        for (int l = 0; l < L; ++l) { sc[l] = __expf(sc[l] - m); den += sc[l]; }
        float wg = w * __builtin_amdgcn_rcpf(den);
#pragma unroll
        for (int l = 0; l < L; ++l) {
            float a = sc[l] * wg;
#pragma unroll
            for (int i = 0; i < 8; ++i) u[i] = fmaf(a, (float)h[l][i], u[i]);
        }
    };

    float wA, wB; half8 kA[L], hA[L], kB[L], hB[L];
    ldb(0, wA, kA, hA);
    for (int b = 0; b < nE; b += 8) {
        ldb(b + 4, wB, kB, hB);
        cmp(wA, kA, hA);
        ldb(b + 8, wA, kA, hA);
        cmp(wB, kB, hB);
    }
    // reduce across the 4 edge-slots
#pragma unroll
    for (int i = 0; i < 8; ++i) {
        u[i] += __shfl_xor(u[i], 16);
        u[i] += __shfl_xor(u[i], 32);
    }
    if (qe == 0) {
        half8 o;
#pragma unroll
        for (int i = 0; i < 8; ++i) o[i] = (f16)(dvd * u[i]);
        *(half8*)(uh + (size_t)d * 128 + le * 8) = o;
    }
}

extern "C" void kernel_launch(void* const* d_in, const int* in_sizes, int n_in,
                              void* d_out, int out_size, void* d_ws, size_t ws_size,
                              hipStream_t stream) {
    (void)in_sizes; (void)n_in; (void)out_size; (void)ws_size;
    const float* x  = (const float*)d_in[0];
    const int*   ei = (const int*)d_in[1];
    const float* W1 = (const float*)d_in[2];
    const float* b1 = (const float*)d_in[3];
    const float* Wq = (const float*)d_in[4];
    const float* bq = (const float*)d_in[5];
    const float* Wk = (const float*)d_in[6];
    const float* bk = (const float*)d_in[7];
    const float* Wv = (const float*)d_in[8];
    const float* bv = (const float*)d_in[9];
    const float* W2 = (const float*)d_in[10];
    const float* b2 = (const float*)d_in[11];
    float* out = (float*)d_out;

    // workspace layout (4-byte words)
    int*    cnt     = (int*)d_ws;                  // 16384
    int*    fill    = cnt + 16384;                 // 16384 (cnt+fill zeroed together)
    int*    rowptr  = fill + 16384;                // 16384 (NN+1)
    int*    esorted = rowptr + 16384;              // 163840
    float*  dinv    = (float*)(esorted + 163840);  // 16384
    float*  srow    = dinv + 16384;                // 16384
    f16*    pack    = (f16*)(srow + 16384);        // NN x 768 halves
    f16*    Sh      = pack + (size_t)NN * PSTR;    // N128
    f16*    qh      = Sh + N128;                   // N128
    f16*    uh      = qh + N128;                   // N128
    f16*    Wt      = uh + N128;                   // 11 x 16384

    prep_fused<<<43, 256, 0, stream>>>(W1, Wq, Wk, Wv, W2, Wt, (int4*)cnt);
    cnt_count<<<(EE + 255) / 256, 256, 0, stream>>>(ei + EE, cnt);
    scan_rowptr<<<1, 256, 0, stream>>>(cnt, rowptr, dinv);
    scatter_edges<<<(EE + 255) / 256, 256, 0, stream>>>(ei, rowptr, fill, esorted);

    const int gx = (NN + 63) / 64;  // 157
    auto WT = [&](int m) { return Wt + (size_t)m * 16384; };  // 0=W1,1..3=Wq,4..6=Wk,7..9=Wv,10=W2
    auto H  = [&](int lev) { return pack + HOFF + lev * 128; };  // h-level base (stride PSTR)
    auto K  = [&](int lev) { return pack + lev * 128; };         // k-level base (stride PSTR)

    {   // h0 = relu(x @ W1 + b1) -> pack  (reads f32 x directly)
        GJobs jobs{};
        jobs.j[0] = {x, WT(0), b1, nullptr, H(0), HID, PSTR, 1, 1, nullptr, nullptr};
        gemm_mfma<<<dim3(gx, 1), 256, 0, stream>>>(jobs, NN);
    }

    const int nblocks = (NN * 64 + 255) / 256;

    // ---- layer 1 (L=1: softmax over 1 level == identity -> GCN, deferred Wv1) ----
    sgather5<<<nblocks, 256, 0, stream>>>(rowptr, esorted, dinv, pack + HOFF, Sh, srow);
    {   // h1 = relu(S @ Wv1 + srow*bv1) -> pack
        GJobs jobs{};
        jobs.j[0] = {Sh, WT(7), bv, srow, H(1), HID, PSTR, 1, 0, nullptr, nullptr};
        gemm_mfma<<<dim3(gx, 1), 256, 0, stream>>>(jobs, NN);
    }

    // ---- layers 2,3: q/k GEMMs -> attention (aggregate raw h) -> deferred Wv GEMM ----
    for (int l = 1; l < 3; ++l) {
        int L = l + 1;
        GJobs jobs{};
        jobs.j[0] = {H(L - 1), WT(1 + l), bq + l * HID, nullptr, qh, PSTR, HID, 2, 0, nullptr, nullptr};
        for (int lev = 0; lev < L; ++lev)
            jobs.j[1 + lev] = {H(lev), WT(4 + l), bk + l * HID, nullptr, K(lev), PSTR, PSTR, 2, 0, nullptr, nullptr};
        gemm_mfma<<<dim3(gx, 1 + L), 256, 0, stream>>>(jobs, NN);

        if (L == 2) node_attn5<2><<<nblocks, 256, 0, stream>>>(rowptr, esorted, dinv, qh, pack, uh);
        if (L == 3) node_attn5<3><<<nblocks, 256, 0, stream>>>(rowptr, esorted, dinv, qh, pack, uh);

        GJobs vjob{};
        if (L == 2) {
            // h2 = relu(u @ Wv2 + srow*bv2) -> pack
            vjob.j[0] = {uh, WT(7 + l), bv + l * HID, srow, H(2), HID, PSTR, 1, 0, nullptr, nullptr};
        } else {
            // fused: h3 = relu(u @ Wv3 + srow*bv3); out = log_softmax(h3 @ W2 + b2)
            vjob.j[0] = {uh, WT(7 + l), bv + l * HID, srow, out, HID, 64, 3, 0, WT(10), b2};
        }
        gemm_mfma<<<dim3(gx, 1), 256, 0, stream>>>(vjob, NN);
    }
}